// Round 4
// baseline (439.892 us; speedup 1.0000x reference)
//
#include <hip/hip_runtime.h>
#include <math.h>

// x: [28, 256, 128, 128] fp32; group lens {4,3,4,4,3,4,2,4} (starts = prefix).
// Group slab [L,256,16384] viewed [256,L,16384]: cluster c uses slab rows
// c*L..c*L+L-1 (each 16384 floats). out[g, c*L+q, :] =
//   sum_k softmax_k(dot(row_q,row_k)/16) * row_k  for c*L+q < 256.
//
// Single persistent kernel: items = (cluster, chunk), 620 clusters x 8 chunks.
// Each block stages its chunk of the L rows in LDS, publishes partial gram
// sums, syncs with its 7 sibling chunk-blocks via a per-cluster counter
// (device-scope release/acquire), then finishes softmax + weighted sum from
// LDS. x is read exactly once from HBM; out written once.

#define DIMD   16384
#define NCH    256
#define NCHUNK 8
#define CHUNKF 2048            // floats per row per chunk
#define NCLUST 620
#define NITEMS (NCLUST * NCHUNK)   // 4960
#define CNT_OFF_FLOATS 36928       // counters start after packed partials

template <int L>
__device__ __forceinline__ void do_item(const float* __restrict__ base,
                                        float* __restrict__ outp,
                                        float* __restrict__ part_c,   // cluster's partials, stride NP per chunk
                                        unsigned int* __restrict__ cnt,
                                        int chunk, int nout,
                                        int tid, int lane, int wave,
                                        float* __restrict__ lds,      // [4][CHUNKF]
                                        float (*__restrict__ red)[10],
                                        float (*__restrict__ w_lds)[4],
                                        float* __restrict__ S_l) {
    constexpr int NP = L * (L + 1) / 2;

    // ---- phase 1: load chunk, stash to LDS, partial gram ----
    float acc[NP];
    #pragma unroll
    for (int p = 0; p < NP; ++p) acc[p] = 0.f;

    #pragma unroll
    for (int i = 0; i < 2; ++i) {
        const int e4 = i * 256 + tid;          // 512 float4 per row-chunk
        float4 v[L];
        #pragma unroll
        for (int k = 0; k < L; ++k) v[k] = ((const float4*)(base + (size_t)k * DIMD))[e4];
        #pragma unroll
        for (int k = 0; k < L; ++k) ((float4*)(lds + k * CHUNKF))[e4] = v[k];
        int idx = 0;
        #pragma unroll
        for (int a = 0; a < L; ++a) {
            #pragma unroll
            for (int b = a; b < L; ++b) {
                acc[idx] = fmaf(v[a].x, v[b].x, acc[idx]);
                acc[idx] = fmaf(v[a].y, v[b].y, acc[idx]);
                acc[idx] = fmaf(v[a].z, v[b].z, acc[idx]);
                acc[idx] = fmaf(v[a].w, v[b].w, acc[idx]);
                ++idx;
            }
        }
    }

    #pragma unroll
    for (int p = 0; p < NP; ++p) {
        float s = acc[p];
        #pragma unroll
        for (int off = 32; off > 0; off >>= 1) s += __shfl_down(s, off, 64);
        if (lane == 0) red[wave][p] = s;
    }
    __syncthreads();

    // ---- publish partials + sync with sibling chunk-blocks ----
    if (tid == 0) {
        #pragma unroll
        for (int p = 0; p < NP; ++p)
            part_c[chunk * NP + p] = red[0][p] + red[1][p] + red[2][p] + red[3][p];
        __hip_atomic_fetch_add(cnt, 1u, __ATOMIC_RELEASE, __HIP_MEMORY_SCOPE_AGENT);
        while (__hip_atomic_load(cnt, __ATOMIC_ACQUIRE, __HIP_MEMORY_SCOPE_AGENT) < NCHUNK)
            __builtin_amdgcn_s_sleep(1);
    }
    __syncthreads();

    if (tid < NP) {
        float s = 0.f;
        #pragma unroll
        for (int ch = 0; ch < NCHUNK; ++ch)
            s += __hip_atomic_load(&part_c[ch * NP + tid], __ATOMIC_RELAXED,
                                   __HIP_MEMORY_SCOPE_AGENT);
        S_l[tid] = s * 0.0625f;   // 1/sqrt(256)
    }
    __syncthreads();

    if (tid < L) {   // thread q: softmax row q
        float Sq[L];
        #pragma unroll
        for (int k = 0; k < L; ++k) {
            const int a = tid < k ? tid : k;
            const int b = tid < k ? k : tid;
            Sq[k] = S_l[a * L - a * (a - 1) / 2 + (b - a)];
        }
        float m = Sq[0];
        #pragma unroll
        for (int k = 1; k < L; ++k) m = fmaxf(m, Sq[k]);
        float e[L], den = 0.f;
        #pragma unroll
        for (int k = 0; k < L; ++k) { e[k] = expf(Sq[k] - m); den += e[k]; }
        const float inv = 1.0f / den;
        #pragma unroll
        for (int k = 0; k < L; ++k) w_lds[tid][k] = e[k] * inv;
    }
    __syncthreads();

    // ---- phase 2: weighted sum from LDS ----
    for (int q = 0; q < nout; ++q) {
        float w[L];
        #pragma unroll
        for (int k = 0; k < L; ++k) w[k] = w_lds[q][k];
        #pragma unroll
        for (int i = 0; i < 2; ++i) {
            const int e4 = i * 256 + tid;
            float4 o = {0.f, 0.f, 0.f, 0.f};
            #pragma unroll
            for (int k = 0; k < L; ++k) {
                const float4 d = ((const float4*)(lds + k * CHUNKF))[e4];
                o.x = fmaf(w[k], d.x, o.x);
                o.y = fmaf(w[k], d.y, o.y);
                o.z = fmaf(w[k], d.z, o.z);
                o.w = fmaf(w[k], d.w, o.w);
            }
            ((float4*)(outp + (size_t)q * DIMD))[e4] = o;
        }
    }
}

__global__ __launch_bounds__(256, 4) void attfusion_fused(const float* __restrict__ x,
                                                          float* __restrict__ out,
                                                          float* __restrict__ ws,
                                                          int grid) {
    __shared__ float lds[4 * CHUNKF];     // 32 KB
    __shared__ float red[4][10];
    __shared__ float w_lds[4][4];
    __shared__ float S_l[10];

    const int lens[8]   = {4, 3, 4, 4, 3, 4, 2, 4};
    const int starts[8] = {0, 4, 7, 11, 15, 18, 22, 24};
    const int coff[9]   = {0, 64, 150, 214, 278, 364, 428, 556, 620};
    // packed partial base per group (floats): 8 chunks * sum(clusters*NP)
    const int poff[8]   = {0, 5120, 9248, 14368, 19488, 23616, 28736, 31808};
    const int npg[8]    = {10, 6, 10, 10, 6, 10, 3, 10};

    unsigned int* counters = (unsigned int*)(ws + CNT_OFF_FLOATS);
    const int tid = threadIdx.x, lane = tid & 63, wave = tid >> 6;

    for (int item = blockIdx.x; item < NITEMS; item += grid) {
        __syncthreads();   // guard LDS reuse across iterations
        const int cluster = item >> 3;
        const int chunk   = item & 7;
        int g = 0;
        while (cluster >= coff[g + 1]) ++g;
        const int c = cluster - coff[g];
        const int L = lens[g];

        const float* base = x + ((size_t)starts[g] * NCH + (size_t)c * L) * DIMD
                              + (size_t)chunk * CHUNKF;
        float* outp = out + ((size_t)g * NCH + (size_t)c * L) * DIMD
                          + (size_t)chunk * CHUNKF;
        float* part_c = ws + poff[g] + (size_t)c * NCHUNK * npg[g];
        unsigned int* cnt = counters + cluster;
        const int nout = min(L, NCH - c * L);

        if (L == 4)      do_item<4>(base, outp, part_c, cnt, chunk, nout, tid, lane, wave, lds, red, w_lds, S_l);
        else if (L == 3) do_item<3>(base, outp, part_c, cnt, chunk, nout, tid, lane, wave, lds, red, w_lds, S_l);
        else             do_item<2>(base, outp, part_c, cnt, chunk, nout, tid, lane, wave, lds, red, w_lds, S_l);
    }
}

extern "C" void kernel_launch(void* const* d_in, const int* in_sizes, int n_in,
                              void* d_out, int out_size, void* d_ws, size_t ws_size,
                              hipStream_t stream) {
    const float* x = (const float*)d_in[0];
    float* out = (float*)d_out;
    float* ws = (float*)d_ws;

    int dev = 0;
    hipGetDevice(&dev);
    int ncu = 256;
    hipDeviceGetAttribute(&ncu, hipDeviceAttributeMultiprocessorCount, dev);
    int occ = 4;
    hipOccupancyMaxActiveBlocksPerMultiprocessor(&occ, attfusion_fused, 256, 0);
    if (occ < 1) occ = 1;
    if (occ > 4) occ = 4;                    // LDS-limited design point
    long G = (long)occ * (long)ncu;
    if (G > NITEMS) G = NITEMS;
    G = (G / NCHUNK) * NCHUNK;               // whole clusters per sweep
    if (G < NCHUNK) G = NCHUNK;

    // zero per-cluster counters (graph-capturable)
    hipMemsetAsync((char*)d_ws + CNT_OFF_FLOATS * sizeof(float), 0,
                   NCLUST * sizeof(unsigned int), stream);
    attfusion_fused<<<dim3((unsigned)G), dim3(256), 0, stream>>>(x, out, ws, (int)G);
}

// Round 6
// 68.045 us; speedup vs baseline: 6.4647x; 6.4647x over previous
//
#include <hip/hip_runtime.h>
#include <math.h>

// x: [28, 256, 128, 128] fp32; group lens {4,3,4,4,3,4,2,4} (starts = prefix).
// Group slab [L,256,16384] viewed [256,L,16384]: cluster c uses slab rows
// c*L..c*L+L-1 (16384 floats each). out[g, c*L+q, :] =
//   sum_k softmax_k(dot(row_q,row_k)/16) * row_k  for c*L+q < 256.
//
// Two-pass:
//   A: per-(cluster, chunk) partial gram sums -> d_ws (overwrite, no atomics).
//   B: sum partials, redundant per-thread softmax, weighted sum streamed out
//      with NONTEMPORAL stores so `out` doesn't evict x from the 256MB LLC
//      (A's 134MB x + B's 134MB out > 256MB otherwise).

#define DIMD   16384   // floats per row
#define NCH    256
#define NCHUNK 8
#define CHUNK4 512     // float4 per chunk (2048 floats)
#define MAXNP  10
#define NCLUST 620

typedef float f32x4 __attribute__((ext_vector_type(4)));

__device__ __forceinline__ int group_of(int cluster, int& c) {
    const int coff[9] = {0, 64, 150, 214, 278, 364, 428, 556, 620};
    int g = 0;
    while (cluster >= coff[g + 1]) ++g;
    c = cluster - coff[g];
    return g;
}

// ---------------- Kernel A: partial gram ----------------
template <int L>
__device__ __forceinline__ void gram_partial(const float* __restrict__ base, int c, int chunk,
                                             float* __restrict__ outp, int tid) {
    constexpr int NP = L * (L + 1) / 2;
    __shared__ float red[4][NP];
    const int lane = tid & 63, wave = tid >> 6;

    const float4* rows[L];
    #pragma unroll
    for (int k = 0; k < L; ++k)
        rows[k] = (const float4*)(base + (size_t)(c * L + k) * DIMD) + chunk * CHUNK4;

    float acc[NP];
    #pragma unroll
    for (int p = 0; p < NP; ++p) acc[p] = 0.f;

    #pragma unroll
    for (int i = 0; i < 2; ++i) {
        const int e4 = i * 256 + tid;
        float4 v[L];
        #pragma unroll
        for (int k = 0; k < L; ++k) v[k] = rows[k][e4];
        int idx = 0;
        #pragma unroll
        for (int a = 0; a < L; ++a) {
            #pragma unroll
            for (int b = a; b < L; ++b) {
                acc[idx] = fmaf(v[a].x, v[b].x, acc[idx]);
                acc[idx] = fmaf(v[a].y, v[b].y, acc[idx]);
                acc[idx] = fmaf(v[a].z, v[b].z, acc[idx]);
                acc[idx] = fmaf(v[a].w, v[b].w, acc[idx]);
                ++idx;
            }
        }
    }

    #pragma unroll
    for (int p = 0; p < NP; ++p) {
        float v = acc[p];
        #pragma unroll
        for (int off = 32; off > 0; off >>= 1) v += __shfl_down(v, off, 64);
        if (lane == 0) red[wave][p] = v;
    }
    __syncthreads();
    if (tid < NP) outp[tid] = red[0][tid] + red[1][tid] + red[2][tid] + red[3][tid];
}

__global__ __launch_bounds__(256) void gram_kernel(const float* __restrict__ x,
                                                   float* __restrict__ ws) {
    const int lens[8]   = {4, 3, 4, 4, 3, 4, 2, 4};
    const int starts[8] = {0, 4, 7, 11, 15, 18, 22, 24};
    const int cluster = blockIdx.x >> 3;
    const int chunk   = blockIdx.x & 7;
    int c; const int g = group_of(cluster, c);
    const float* base = x + (size_t)starts[g] * NCH * DIMD;
    float* outp = ws + ((size_t)cluster * NCHUNK + chunk) * MAXNP;
    const int L = lens[g];
    if (L == 4)      gram_partial<4>(base, c, chunk, outp, threadIdx.x);
    else if (L == 3) gram_partial<3>(base, c, chunk, outp, threadIdx.x);
    else             gram_partial<2>(base, c, chunk, outp, threadIdx.x);
}

// ---------------- Kernel B: softmax + weighted sum (NT stores) ----------------
template <int L>
__device__ __forceinline__ void fuse_chunk(const float* __restrict__ base,
                                           float* __restrict__ outg,
                                           const float* __restrict__ wsc,
                                           int c, int chunk, int tid) {
    constexpr int NP = L * (L + 1) / 2;
    __shared__ float S_l[NP];

    if (tid < NP) {
        float s = 0.f;
        #pragma unroll
        for (int ch = 0; ch < NCHUNK; ++ch) s += wsc[ch * MAXNP + tid];
        S_l[tid] = s * 0.0625f;   // 1/sqrt(256)
    }
    __syncthreads();

    // every thread computes the tiny softmax redundantly (no serialization)
    float S[L][L];
    {
        int idx = 0;
        #pragma unroll
        for (int a = 0; a < L; ++a)
            #pragma unroll
            for (int b = a; b < L; ++b) { float s = S_l[idx]; S[a][b] = s; S[b][a] = s; ++idx; }
    }
    float W[L][L];
    #pragma unroll
    for (int q = 0; q < L; ++q) {
        float m = S[q][0];
        #pragma unroll
        for (int k = 1; k < L; ++k) m = fmaxf(m, S[q][k]);
        float den = 0.f;
        #pragma unroll
        for (int k = 0; k < L; ++k) { W[q][k] = expf(S[q][k] - m); den += W[q][k]; }
        const float inv = 1.0f / den;
        #pragma unroll
        for (int k = 0; k < L; ++k) W[q][k] *= inv;
    }

    const int nout = min(L, NCH - c * L);
    const float4* rows[L];
    #pragma unroll
    for (int k = 0; k < L; ++k)
        rows[k] = (const float4*)(base + (size_t)(c * L + k) * DIMD) + chunk * CHUNK4;

    #pragma unroll
    for (int i = 0; i < 2; ++i) {
        const int e4 = i * 256 + tid;
        float4 v[L];
        #pragma unroll
        for (int k = 0; k < L; ++k) v[k] = rows[k][e4];
        for (int q = 0; q < nout; ++q) {
            float4 o = {0.f, 0.f, 0.f, 0.f};
            #pragma unroll
            for (int k = 0; k < L; ++k) {
                const float w = W[q][k];
                o.x = fmaf(w, v[k].x, o.x);
                o.y = fmaf(w, v[k].y, o.y);
                o.z = fmaf(w, v[k].z, o.z);
                o.w = fmaf(w, v[k].w, o.w);
            }
            f32x4* dst = (f32x4*)((float4*)(outg + (size_t)(c * L + q) * DIMD) + chunk * CHUNK4 + e4);
            f32x4 ov = {o.x, o.y, o.z, o.w};
            __builtin_nontemporal_store(ov, dst);   // don't evict x from LLC
        }
    }
}

__global__ __launch_bounds__(256) void fuse_kernel(const float* __restrict__ x,
                                                   const float* __restrict__ ws,
                                                   float* __restrict__ out) {
    const int lens[8]   = {4, 3, 4, 4, 3, 4, 2, 4};
    const int starts[8] = {0, 4, 7, 11, 15, 18, 22, 24};
    const int cluster = blockIdx.x >> 3;
    const int chunk   = blockIdx.x & 7;
    int c; const int g = group_of(cluster, c);
    const float* base = x + (size_t)starts[g] * NCH * DIMD;
    float* outg = out + (size_t)g * NCH * DIMD;
    const float* wsc = ws + (size_t)cluster * NCHUNK * MAXNP;
    const int L = lens[g];
    if (L == 4)      fuse_chunk<4>(base, outg, wsc, c, chunk, threadIdx.x);
    else if (L == 3) fuse_chunk<3>(base, outg, wsc, c, chunk, threadIdx.x);
    else             fuse_chunk<2>(base, outg, wsc, c, chunk, threadIdx.x);
}

extern "C" void kernel_launch(void* const* d_in, const int* in_sizes, int n_in,
                              void* d_out, int out_size, void* d_ws, size_t ws_size,
                              hipStream_t stream) {
    const float* x = (const float*)d_in[0];
    float* out = (float*)d_out;
    float* ws = (float*)d_ws;
    gram_kernel<<<dim3(NCLUST * NCHUNK), dim3(256), 0, stream>>>(x, ws);
    fuse_kernel<<<dim3(NCLUST * NCHUNK), dim3(256), 0, stream>>>(x, ws, out);
}